// Round 7
// baseline (105.708 us; speedup 1.0000x reference)
//
#include <hip/hip_runtime.h>

constexpr int BB   = 2;
constexpr int NN   = 50000;
constexpr int EE   = 600000;
constexpr int CDIM = 128;
constexpr int SEGS = BB * NN;   // 100000
constexpr int CAP  = 32;        // max degree = 1 + Poisson(5); P(>=32) ~ 1e-10
constexpr int EBLK = (EE + 255) / 256;                  // edge-bin blocks
constexpr int CBLK = (SEGS * CDIM + 8191) / 8192;       // node-cvt blocks (32 f/thr)

typedef __attribute__((ext_vector_type(8))) short bf16x8;
typedef __attribute__((ext_vector_type(4))) float f32x4;

__device__ __forceinline__ unsigned short f2bf(float f) {
    unsigned u = __builtin_bit_cast(unsigned, f);
    return (unsigned short)((u + 0x7FFFu + ((u >> 16) & 1u)) >> 16);  // RNE
}
__device__ __forceinline__ float bf2f(unsigned short v) {
    unsigned u = ((unsigned)v) << 16;
    return __builtin_bit_cast(float, u);
}

// ---------------------------------------------------------------------------
// binscatter_k — three block roles:
//   [0, EBLK):       bin edges: slot=count[seg]++; payload=src|(rel<<16)
//   EBLK:            W (f32) -> bf16 MFMA-B-fragment-linear layout in Wbf
//   (EBLK, +CBLK]:   node_states f32 -> bf16 row-major copy in nodeb
// ---------------------------------------------------------------------------
__global__ __launch_bounds__(256) void binscatter_k(
    const int* __restrict__ eidx, unsigned* __restrict__ count,
    unsigned* __restrict__ payload, const float* __restrict__ W,
    unsigned* __restrict__ Wbf, const float* __restrict__ node,
    unsigned short* __restrict__ nodeb)
{
    if (blockIdx.x == EBLK) {
        int t = threadIdx.x;
        #pragma unroll
        for (int i = 0; i < 8; ++i) {
            int u = t * 8 + i;          // 16B unit index, 0..2047
            int l = u & 63, f = u >> 6; // f = n*4 + ks
            int c16 = l & 15, q = l >> 4;
            int col = (f >> 2) * 16 + c16;
            int kb  = (f & 3) * 32 + q * 8;
            const float* wp = W + col * CDIM + kb;
            float4 w0 = *reinterpret_cast<const float4*>(wp);
            float4 w1 = *reinterpret_cast<const float4*>(wp + 4);
            uint4 pk;
            pk.x = (unsigned)f2bf(w0.x) | ((unsigned)f2bf(w0.y) << 16);
            pk.y = (unsigned)f2bf(w0.z) | ((unsigned)f2bf(w0.w) << 16);
            pk.z = (unsigned)f2bf(w1.x) | ((unsigned)f2bf(w1.y) << 16);
            pk.w = (unsigned)f2bf(w1.z) | ((unsigned)f2bf(w1.w) << 16);
            reinterpret_cast<uint4*>(Wbf)[u] = pk;
        }
        return;
    }
    if (blockIdx.x > EBLK) {
        // node f32 -> bf16: each thread converts 32 consecutive floats
        int u = (blockIdx.x - EBLK - 1) * 256 + threadIdx.x;   // 32-float unit
        if (u >= SEGS * CDIM / 32) return;
        const float4* src = reinterpret_cast<const float4*>(node) + (size_t)u * 8;
        uint4* dst = reinterpret_cast<uint4*>(nodeb) + (size_t)u * 4;
        #pragma unroll
        for (int i = 0; i < 4; ++i) {
            float4 a = src[i * 2], b2 = src[i * 2 + 1];
            uint4 pk;
            pk.x = (unsigned)f2bf(a.x) | ((unsigned)f2bf(a.y) << 16);
            pk.y = (unsigned)f2bf(a.z) | ((unsigned)f2bf(a.w) << 16);
            pk.z = (unsigned)f2bf(b2.x) | ((unsigned)f2bf(b2.y) << 16);
            pk.w = (unsigned)f2bf(b2.z) | ((unsigned)f2bf(b2.w) << 16);
            dst[i] = pk;
        }
        return;
    }
    int e = blockIdx.x * 256 + threadIdx.x;
    if (e >= EE) return;
    int b = eidx[e];
    int t = eidx[EE + e];
    int s = eidx[2 * EE + e];
    int r = eidx[3 * EE + e];
    int seg = b * NN + t;
    unsigned slot = atomicAdd(count + seg, 1u);
    if (slot < CAP) payload[(size_t)seg * CAP + slot] = (unsigned)s | ((unsigned)r << 16);
}

// ---------------------------------------------------------------------------
// fused_k<NB>: 512 threads = 8 waves; block owns 16 segments (16x128 tile).
// NB=true: node rows gathered as bf16 (256 B/row, 1 b128 per edge-quarter);
// NB=false: f32 fallback (ws too small). Wave w prefetches its 4 B-frags
// from Wbf to VGPRs; rel (32 KB f32) staged linearly in LDS. Gather: wave w
// owns 2 segments; lane (q=l>>4, c=l&15); quarter q takes edges q, q+4, ...
// Clamped indices + 0/1 weights keep loads branchless. Combine shfl_xor;
// mean fused; x-row -> Xl bf16 XOR-swizzled. MFMA: 4x 16x16x32 per wave.
// ---------------------------------------------------------------------------
template<bool NB>
__global__ __launch_bounds__(512) void fused_k(
    const void* __restrict__ nodev, const float* __restrict__ rel,
    const unsigned* __restrict__ count, const unsigned* __restrict__ payload,
    const unsigned* __restrict__ Wbf, float* __restrict__ out)
{
    __shared__ __align__(16) float Rl[64 * CDIM];           // 32 KB rel f32
    __shared__ __align__(16) unsigned short Xl[16 * CDIM];  // 4 KB swizzled

    const int tid = threadIdx.x;
    const int wav = tid >> 6;
    const int l   = tid & 63;
    const int q   = l >> 4;
    const int c   = l & 15;

    // prefetch this wave's 4 B-fragments (consumed after the barrier)
    bf16x8 bfr[4];
    #pragma unroll
    for (int ks = 0; ks < 4; ++ks)
        bfr[ks] = reinterpret_cast<const bf16x8*>(Wbf)[(wav * 4 + ks) * 64 + l];

    // stage rel -> LDS, linear: 2048 float4, 512 thr x 4
    {
        const float4* src = reinterpret_cast<const float4*>(rel);
        float4* dst = reinterpret_cast<float4*>(Rl);
        #pragma unroll
        for (int i = 0; i < 4; ++i) dst[i * 512 + tid] = src[i * 512 + tid];
    }

    const int seg0 = blockIdx.x * 16 + wav * 2;
    const uint2 c2 = *reinterpret_cast<const uint2*>(count + seg0);  // broadcast
    unsigned pv0 = payload[(size_t)seg0 * CAP + (l & 31)];
    unsigned pv1 = payload[(size_t)(seg0 + 1) * CAP + (l & 31)];

    __syncthreads();  // Rl ready

    #pragma unroll
    for (int si = 0; si < 2; ++si) {
        int seg = seg0 + si;
        unsigned cnt = si ? c2.y : c2.x;
        if (cnt > CAP) cnt = CAP;
        unsigned pv = si ? pv1 : pv0;
        int b = (seg >= NN) ? 1 : 0;

        const float* rb = Rl + c * 8;

        float acc[8];
        #pragma unroll
        for (int i = 0; i < 8; ++i) acc[i] = 0.f;

        for (unsigned base = 0; base < cnt; base += 8) {
            unsigned j0 = base + q, j1 = base + 4 + q;
            unsigned jc0 = (j0 < cnt) ? j0 : (cnt - 1);
            unsigned jc1 = (j1 < cnt) ? j1 : (cnt - 1);
            float w0 = (j0 < cnt) ? 1.f : 0.f;
            float w1 = (j1 < cnt) ? 1.f : 0.f;
            unsigned p0 = __shfl(pv, (int)jc0, 32);
            unsigned p1 = __shfl(pv, (int)jc1, 32);
            int s0 = (int)(p0 & 0xFFFFu), r0 = (int)(p0 >> 16);
            int s1 = (int)(p1 & 0xFFFFu), r1 = (int)(p1 >> 16);

            float4 r0a = *reinterpret_cast<const float4*>(rb + r0 * CDIM);
            float4 r0b = *reinterpret_cast<const float4*>(rb + r0 * CDIM + 4);
            float4 r1a = *reinterpret_cast<const float4*>(rb + r1 * CDIM);
            float4 r1b = *reinterpret_cast<const float4*>(rb + r1 * CDIM + 4);
            float r0f[8] = {r0a.x, r0a.y, r0a.z, r0a.w, r0b.x, r0b.y, r0b.z, r0b.w};
            float r1f[8] = {r1a.x, r1a.y, r1a.z, r1a.w, r1b.x, r1b.y, r1b.z, r1b.w};

            if constexpr (NB) {
                const unsigned short* nb =
                    (const unsigned short*)nodev + (size_t)b * NN * CDIM + c * 8;
                bf16x8 h0 = *reinterpret_cast<const bf16x8*>(nb + (size_t)s0 * CDIM);
                bf16x8 h1 = *reinterpret_cast<const bf16x8*>(nb + (size_t)s1 * CDIM);
                #pragma unroll
                for (int i = 0; i < 8; ++i) {
                    acc[i] = fmaf(w0, bf2f((unsigned short)h0[i]) - r0f[i], acc[i]);
                    acc[i] = fmaf(w1, bf2f((unsigned short)h1[i]) - r1f[i], acc[i]);
                }
            } else {
                const float* nb = (const float*)nodev + (size_t)b * NN * CDIM + c * 8;
                const float* h0 = nb + (size_t)s0 * CDIM;
                const float* h1 = nb + (size_t)s1 * CDIM;
                float4 h0a = *reinterpret_cast<const float4*>(h0);
                float4 h0b = *reinterpret_cast<const float4*>(h0 + 4);
                float4 h1a = *reinterpret_cast<const float4*>(h1);
                float4 h1b = *reinterpret_cast<const float4*>(h1 + 4);
                float h0f[8] = {h0a.x, h0a.y, h0a.z, h0a.w, h0b.x, h0b.y, h0b.z, h0b.w};
                float h1f[8] = {h1a.x, h1a.y, h1a.z, h1a.w, h1b.x, h1b.y, h1b.z, h1b.w};
                #pragma unroll
                for (int i = 0; i < 8; ++i) {
                    acc[i] = fmaf(w0, h0f[i] - r0f[i], acc[i]);
                    acc[i] = fmaf(w1, h1f[i] - r1f[i], acc[i]);
                }
            }
        }

        // combine quarters: all lanes end with the full 128-dim sum
        #pragma unroll
        for (int i = 0; i < 8; ++i) {
            acc[i] += __shfl_xor(acc[i], 16);
            acc[i] += __shfl_xor(acc[i], 32);
        }

        if (q == 0) {
            float inv = 1.f / (float)cnt;  // cnt >= 1 (cover edges)
            int row = wav * 2 + si;
            uint4 pk;
            pk.x = (unsigned)f2bf(acc[0] * inv) | ((unsigned)f2bf(acc[1] * inv) << 16);
            pk.y = (unsigned)f2bf(acc[2] * inv) | ((unsigned)f2bf(acc[3] * inv) << 16);
            pk.z = (unsigned)f2bf(acc[4] * inv) | ((unsigned)f2bf(acc[5] * inv) << 16);
            pk.w = (unsigned)f2bf(acc[6] * inv) | ((unsigned)f2bf(acc[7] * inv) << 16);
            int off = (row * 256 + c * 16) ^ ((row & 7) << 4);
            *reinterpret_cast<uint4*>((char*)Xl + off) = pk;
        }
    }

    __syncthreads();  // x-tile staged

    // A-frags: lane row = c, k = ks*32 + q*8 + j
    bf16x8 afr[4];
    #pragma unroll
    for (int ks = 0; ks < 4; ++ks) {
        int off = (c * 256 + ks * 64 + q * 16) ^ ((c & 7) << 4);
        afr[ks] = *reinterpret_cast<const bf16x8*>((const char*)Xl + off);
    }

    f32x4 accv = (f32x4){0.f, 0.f, 0.f, 0.f};
    #pragma unroll
    for (int ks = 0; ks < 4; ++ks)
        accv = __builtin_amdgcn_mfma_f32_16x16x32_bf16(afr[ks], bfr[ks], accv, 0, 0, 0);

    // store: row = blk*16 + q*4 + j, col = wav*16 + c
    size_t rowbase = (size_t)blockIdx.x * 16;
    #pragma unroll
    for (int j = 0; j < 4; ++j)
        out[(rowbase + q * 4 + j) * CDIM + wav * 16 + c] = accv[j];
}

extern "C" void kernel_launch(void* const* d_in, const int* in_sizes, int n_in,
                              void* d_out, int out_size, void* d_ws, size_t ws_size,
                              hipStream_t stream) {
    const float* node = (const float*)d_in[0];
    const int*   eidx = (const int*)d_in[1];
    const float* rel  = (const float*)d_in[2];
    const float* W    = (const float*)d_in[3];
    float* out = (float*)d_out;

    // ws: count u32[SEGS] @0; payload u32[SEGS*CAP] @400000; Wbf @13200000
    //     nodeb bf16[SEGS*CDIM] @13232768 (ends 38832768)
    unsigned* count   = (unsigned*)d_ws;
    unsigned* payload = (unsigned*)((char*)d_ws + 400000);
    unsigned* Wbf     = (unsigned*)((char*)d_ws + 13200000);
    unsigned short* nodeb = (unsigned short*)((char*)d_ws + 13232768);
    const size_t NEED = 13232768ull + (size_t)SEGS * CDIM * 2;
    const bool use_bf = (ws_size >= NEED);

    hipMemsetAsync(count, 0, (size_t)SEGS * sizeof(unsigned), stream);

    int grid = use_bf ? (EBLK + 1 + CBLK) : (EBLK + 1);
    binscatter_k<<<grid, 256, 0, stream>>>(eidx, count, payload, W, Wbf, node, nodeb);

    if (use_bf)
        fused_k<true><<<SEGS / 16, 512, 0, stream>>>(nodeb, rel, count, payload, Wbf, out);
    else
        fused_k<false><<<SEGS / 16, 512, 0, stream>>>(node, rel, count, payload, Wbf, out);
}

// Round 10
// 94.931 us; speedup vs baseline: 1.1135x; 1.1135x over previous
//
#include <hip/hip_runtime.h>

constexpr int BB   = 2;
constexpr int NN   = 50000;
constexpr int EE   = 600000;
constexpr int CDIM = 128;
constexpr int SEGS = BB * NN;   // 100000
constexpr int CAP  = 32;        // max degree = 1 + Poisson(5); P(>=32) ~ 1e-10
constexpr int EBLK = (EE + 255) / 256;  // edge-bin blocks

typedef __attribute__((ext_vector_type(8))) short bf16x8;
typedef __attribute__((ext_vector_type(4))) float f32x4;

__device__ __forceinline__ unsigned short f2bf(float f) {
    unsigned u = __builtin_bit_cast(unsigned, f);
    return (unsigned short)((u + 0x7FFFu + ((u >> 16) & 1u)) >> 16);  // RNE
}
__device__ __forceinline__ float bf2f(unsigned short v) {
    unsigned u = ((unsigned)v) << 16;
    return __builtin_bit_cast(float, u);
}

// ---------------------------------------------------------------------------
// binscatter_k — two block roles:
//   [0, EBLK): bin edges: slot=count[seg]++; payload=src|(rel<<16)
//   EBLK:      W (f32) -> bf16 MFMA-B-fragment-linear Wbf, and
//              rel (f32) -> bf16 linear relb (64x128 = 1024 uint4, 16 KB)
// ---------------------------------------------------------------------------
__global__ __launch_bounds__(256) void binscatter_k(
    const int* __restrict__ eidx, unsigned* __restrict__ count,
    unsigned* __restrict__ payload, const float* __restrict__ W,
    unsigned* __restrict__ Wbf, const float* __restrict__ rel,
    unsigned* __restrict__ relb)
{
    if (blockIdx.x == EBLK) {
        int t = threadIdx.x;
        #pragma unroll
        for (int i = 0; i < 8; ++i) {
            int u = t * 8 + i;          // 16B unit index, 0..2047
            int l = u & 63, f = u >> 6; // f = n*4 + ks
            int c16 = l & 15, q = l >> 4;
            int col = (f >> 2) * 16 + c16;
            int kb  = (f & 3) * 32 + q * 8;
            const float* wp = W + col * CDIM + kb;
            float4 w0 = *reinterpret_cast<const float4*>(wp);
            float4 w1 = *reinterpret_cast<const float4*>(wp + 4);
            uint4 pk;
            pk.x = (unsigned)f2bf(w0.x) | ((unsigned)f2bf(w0.y) << 16);
            pk.y = (unsigned)f2bf(w0.z) | ((unsigned)f2bf(w0.w) << 16);
            pk.z = (unsigned)f2bf(w1.x) | ((unsigned)f2bf(w1.y) << 16);
            pk.w = (unsigned)f2bf(w1.z) | ((unsigned)f2bf(w1.w) << 16);
            reinterpret_cast<uint4*>(Wbf)[u] = pk;
        }
        // rel -> bf16 linear: 1024 uint4 units total, 4 per thread  [R8 BUGFIX]
        const float4* rs = reinterpret_cast<const float4*>(rel);
        uint4* rd = reinterpret_cast<uint4*>(relb);
        #pragma unroll
        for (int i = 0; i < 4; ++i) {
            int u = t * 4 + i;          // 0..1023
            float4 a = rs[u * 2], b2 = rs[u * 2 + 1];
            uint4 pk;
            pk.x = (unsigned)f2bf(a.x) | ((unsigned)f2bf(a.y) << 16);
            pk.y = (unsigned)f2bf(a.z) | ((unsigned)f2bf(a.w) << 16);
            pk.z = (unsigned)f2bf(b2.x) | ((unsigned)f2bf(b2.y) << 16);
            pk.w = (unsigned)f2bf(b2.z) | ((unsigned)f2bf(b2.w) << 16);
            rd[u] = pk;
        }
        return;
    }
    int e = blockIdx.x * 256 + threadIdx.x;
    if (e >= EE) return;
    int b = eidx[e];
    int t = eidx[EE + e];
    int s = eidx[2 * EE + e];
    int r = eidx[3 * EE + e];
    int seg = b * NN + t;
    unsigned slot = atomicAdd(count + seg, 1u);
    if (slot < CAP) payload[(size_t)seg * CAP + slot] = (unsigned)s | ((unsigned)r << 16);
}

// ---------------------------------------------------------------------------
// fused_k: 256 threads = 4 waves; block owns 16 segments (one 16x128 tile).
// Gather: each 16-lane QUARTER owns one segment end-to-end (lane c holds
// dims c*8..c*8+7) -> no cross-lane combine. j-loop over edges with a
// quarter-uniform predicate `if (j < cnt)`; every iteration issues 2
// independent float4 node loads per lane (4 edge-rows per wave instr), no
// load->load deps -> deep MLP. rel is bf16 in LDS, padded stride 272 B.
// x-row -> Xl bf16 XOR-swizzled; mean fused. MFMA: wave w loads its 8
// B-frags from L2-hot Wbf (after barrier), computes cols w*32..w*32+31.
// LDS = 17.4K (Rl) + 4K (Xl) -> 7 blocks/CU = 28 waves/CU cap.
// ---------------------------------------------------------------------------
__global__ __launch_bounds__(256) void fused_k(
    const float* __restrict__ node, const unsigned* __restrict__ relbg,
    const unsigned* __restrict__ count, const unsigned* __restrict__ payload,
    const unsigned* __restrict__ Wbf, float* __restrict__ out)
{
    __shared__ __align__(16) unsigned short Rl[64 * 136];   // 17408 B, 272B stride
    __shared__ __align__(16) unsigned short Xl[16 * CDIM];  // 4 KB swizzled

    const int tid = threadIdx.x;
    const int wav = tid >> 6;
    const int l   = tid & 63;
    const int q   = l >> 4;
    const int c   = l & 15;

    // stage relb (16 KB, L2-hot) into padded LDS: 1024 uint4, 4/thread
    {
        const uint4* src = reinterpret_cast<const uint4*>(relbg);
        #pragma unroll
        for (int i = 0; i < 4; ++i) {
            int u = i * 256 + tid;
            int row = u >> 4, cu = u & 15;
            *reinterpret_cast<uint4*>((char*)Rl + row * 272 + cu * 16) = src[u];
        }
    }

    const int seg = blockIdx.x * 16 + wav * 4 + q;
    const int b   = (seg >= NN) ? 1 : 0;
    unsigned cnt = count[seg];
    if (cnt > CAP) cnt = CAP;
    unsigned pv0 = payload[(size_t)seg * CAP + c];
    unsigned pv1 = payload[(size_t)seg * CAP + 16 + c];

    // wave-max edge count (all 4 quarters)
    unsigned maxc = cnt;
    { unsigned o = __shfl_xor(maxc, 16); if (o > maxc) maxc = o;
      o = __shfl_xor(maxc, 32); if (o > maxc) maxc = o; }

    __syncthreads();  // Rl ready

    const float* nb = node + (size_t)b * NN * CDIM + c * 8;
    const char* rlb = (const char*)Rl + c * 16;

    float acc[8];
    #pragma unroll
    for (int i = 0; i < 8; ++i) acc[i] = 0.f;

    for (unsigned j = 0; j < maxc; ++j) {
        unsigned p = __shfl((j & 16u) ? pv1 : pv0, (int)(j & 15u), 16);
        if (j < cnt) {
            int s = (int)(p & 0xFFFFu);
            int r = (int)((p >> 16) & 63u);
            const float* h = nb + (size_t)s * CDIM;
            float4 ha = *reinterpret_cast<const float4*>(h);
            float4 hb = *reinterpret_cast<const float4*>(h + 4);
            bf16x8 rv = *reinterpret_cast<const bf16x8*>(rlb + r * 272);
            acc[0] += ha.x - bf2f((unsigned short)rv[0]);
            acc[1] += ha.y - bf2f((unsigned short)rv[1]);
            acc[2] += ha.z - bf2f((unsigned short)rv[2]);
            acc[3] += ha.w - bf2f((unsigned short)rv[3]);
            acc[4] += hb.x - bf2f((unsigned short)rv[4]);
            acc[5] += hb.y - bf2f((unsigned short)rv[5]);
            acc[6] += hb.z - bf2f((unsigned short)rv[6]);
            acc[7] += hb.w - bf2f((unsigned short)rv[7]);
        }
    }

    // mean + bf16 pack; lane c writes its own 16 B of row (wav*4 + q)
    {
        float inv = 1.f / (float)cnt;  // cnt >= 1 (cover edges)
        int row = wav * 4 + q;
        uint4 pk;
        pk.x = (unsigned)f2bf(acc[0] * inv) | ((unsigned)f2bf(acc[1] * inv) << 16);
        pk.y = (unsigned)f2bf(acc[2] * inv) | ((unsigned)f2bf(acc[3] * inv) << 16);
        pk.z = (unsigned)f2bf(acc[4] * inv) | ((unsigned)f2bf(acc[5] * inv) << 16);
        pk.w = (unsigned)f2bf(acc[6] * inv) | ((unsigned)f2bf(acc[7] * inv) << 16);
        int off = (row * 256 + c * 16) ^ ((row & 7) << 4);
        *reinterpret_cast<uint4*>((char*)Xl + off) = pk;
    }

    __syncthreads();  // x-tile staged

    // A-frags: lane row = c, k = ks*32 + q*8 + j
    bf16x8 afr[4];
    #pragma unroll
    for (int ks = 0; ks < 4; ++ks) {
        int off = (c * 256 + ks * 64 + q * 16) ^ ((c & 7) << 4);
        afr[ks] = *reinterpret_cast<const bf16x8*>((const char*)Xl + off);
    }

    // wave computes cols wav*32 .. wav*32+31 (n = wav*2, wav*2+1)
    size_t rowbase = (size_t)blockIdx.x * 16;
    #pragma unroll
    for (int n2 = 0; n2 < 2; ++n2) {
        int n = wav * 2 + n2;
        f32x4 accv = (f32x4){0.f, 0.f, 0.f, 0.f};
        #pragma unroll
        for (int ks = 0; ks < 4; ++ks) {
            bf16x8 bfr = reinterpret_cast<const bf16x8*>(Wbf)[(n * 4 + ks) * 64 + l];
            accv = __builtin_amdgcn_mfma_f32_16x16x32_bf16(afr[ks], bfr, accv, 0, 0, 0);
        }
        #pragma unroll
        for (int j = 0; j < 4; ++j)
            out[(rowbase + q * 4 + j) * CDIM + n * 16 + c] = accv[j];
    }
}

extern "C" void kernel_launch(void* const* d_in, const int* in_sizes, int n_in,
                              void* d_out, int out_size, void* d_ws, size_t ws_size,
                              hipStream_t stream) {
    const float* node = (const float*)d_in[0];
    const int*   eidx = (const int*)d_in[1];
    const float* rel  = (const float*)d_in[2];
    const float* W    = (const float*)d_in[3];
    float* out = (float*)d_out;

    // ws: count u32[SEGS] @0 (400000 B); payload u32[SEGS*CAP] @400000
    //     (12.8 MB, ends 13200000); Wbf 32 KB @13200000; relb 16 KB @13232768
    unsigned* count   = (unsigned*)d_ws;
    unsigned* payload = (unsigned*)((char*)d_ws + 400000);
    unsigned* Wbf     = (unsigned*)((char*)d_ws + 13200000);
    unsigned* relb    = (unsigned*)((char*)d_ws + 13232768);

    hipMemsetAsync(count, 0, (size_t)SEGS * sizeof(unsigned), stream);

    binscatter_k<<<EBLK + 1, 256, 0, stream>>>(eidx, count, payload, W, Wbf, rel, relb);
    fused_k<<<SEGS / 16, 256, 0, stream>>>(node, relb, count, payload, Wbf, out);
}

// Round 12
// 89.894 us; speedup vs baseline: 1.1759x; 1.0560x over previous
//
#include <hip/hip_runtime.h>

constexpr int BB   = 2;
constexpr int NN   = 50000;
constexpr int EE   = 600000;
constexpr int CDIM = 128;
constexpr int SEGS = BB * NN;   // 100000
constexpr int CAP  = 32;        // max degree = 1 + Poisson(5); P(>=32) ~ 1e-10
constexpr int EBLK = (EE + 255) / 256;  // edge-bin blocks

typedef __attribute__((ext_vector_type(8))) short bf16x8;
typedef __attribute__((ext_vector_type(4))) float f32x4;

__device__ __forceinline__ unsigned short f2bf(float f) {
    unsigned u = __builtin_bit_cast(unsigned, f);
    return (unsigned short)((u + 0x7FFFu + ((u >> 16) & 1u)) >> 16);  // RNE
}
__device__ __forceinline__ float bf2f(unsigned short v) {
    unsigned u = ((unsigned)v) << 16;
    return __builtin_bit_cast(float, u);
}

// ---------------------------------------------------------------------------
// binscatter_k — two block roles:
//   [0, EBLK): bin edges: slot=count[seg]++; payload=src|(rel<<16)
//   EBLK:      W (f32) -> bf16 MFMA-B-fragment-linear Wbf, and
//              rel (f32) -> bf16 linear relb (64x128 = 1024 uint4, 16 KB)
// ---------------------------------------------------------------------------
__global__ __launch_bounds__(256) void binscatter_k(
    const int* __restrict__ eidx, unsigned* __restrict__ count,
    unsigned* __restrict__ payload, const float* __restrict__ W,
    unsigned* __restrict__ Wbf, const float* __restrict__ rel,
    unsigned* __restrict__ relb)
{
    if (blockIdx.x == EBLK) {
        int t = threadIdx.x;
        #pragma unroll
        for (int i = 0; i < 8; ++i) {
            int u = t * 8 + i;          // 16B unit index, 0..2047
            int l = u & 63, f = u >> 6; // f = n*4 + ks
            int c16 = l & 15, q = l >> 4;
            int col = (f >> 2) * 16 + c16;
            int kb  = (f & 3) * 32 + q * 8;
            const float* wp = W + col * CDIM + kb;
            float4 w0 = *reinterpret_cast<const float4*>(wp);
            float4 w1 = *reinterpret_cast<const float4*>(wp + 4);
            uint4 pk;
            pk.x = (unsigned)f2bf(w0.x) | ((unsigned)f2bf(w0.y) << 16);
            pk.y = (unsigned)f2bf(w0.z) | ((unsigned)f2bf(w0.w) << 16);
            pk.z = (unsigned)f2bf(w1.x) | ((unsigned)f2bf(w1.y) << 16);
            pk.w = (unsigned)f2bf(w1.z) | ((unsigned)f2bf(w1.w) << 16);
            reinterpret_cast<uint4*>(Wbf)[u] = pk;
        }
        // rel -> bf16 linear: 1024 uint4 units total, 4 per thread
        const float4* rs = reinterpret_cast<const float4*>(rel);
        uint4* rd = reinterpret_cast<uint4*>(relb);
        #pragma unroll
        for (int i = 0; i < 4; ++i) {
            int u = t * 4 + i;          // 0..1023
            float4 a = rs[u * 2], b2 = rs[u * 2 + 1];
            uint4 pk;
            pk.x = (unsigned)f2bf(a.x) | ((unsigned)f2bf(a.y) << 16);
            pk.y = (unsigned)f2bf(a.z) | ((unsigned)f2bf(a.w) << 16);
            pk.z = (unsigned)f2bf(b2.x) | ((unsigned)f2bf(b2.y) << 16);
            pk.w = (unsigned)f2bf(b2.z) | ((unsigned)f2bf(b2.w) << 16);
            rd[u] = pk;
        }
        return;
    }
    int e = blockIdx.x * 256 + threadIdx.x;
    if (e >= EE) return;
    int b = eidx[e];
    int t = eidx[EE + e];
    int s = eidx[2 * EE + e];
    int r = eidx[3 * EE + e];
    int seg = b * NN + t;
    unsigned slot = atomicAdd(count + seg, 1u);
    if (slot < CAP) payload[(size_t)seg * CAP + slot] = (unsigned)s | ((unsigned)r << 16);
}

// ---------------------------------------------------------------------------
// fused_k: 256 threads = 4 waves; block owns 16 segments (one 16x128 tile).
// Gather: each 16-lane QUARTER owns one segment (lane c holds dims
// c*8..c*8+7) -> no cross-lane combine. j-loop unrolled x4 BRANCHLESS:
// 4 clamped payload indices (weight 0/1), then all 8 node float4 loads +
// 4 rel LDS reads issued back-to-back before any accumulate -> ~8 loads
// in flight per wave (4x the previous MLP). Loop trips per-quarter
// (exec-mask divergence; short quarters go idle). rel bf16 in LDS,
// 272 B padded stride. x-row -> Xl bf16 XOR-swizzled; mean fused.
// MFMA: wave w loads its 8 B-frags from L2-hot Wbf, computes cols
// w*32..w*32+31 (8x 16x16x32), stores f32.
// ---------------------------------------------------------------------------
__global__ __launch_bounds__(256) void fused_k(
    const float* __restrict__ node, const unsigned* __restrict__ relbg,
    const unsigned* __restrict__ count, const unsigned* __restrict__ payload,
    const unsigned* __restrict__ Wbf, float* __restrict__ out)
{
    __shared__ __align__(16) unsigned short Rl[64 * 136];   // 17408 B, 272B stride
    __shared__ __align__(16) unsigned short Xl[16 * CDIM];  // 4 KB swizzled

    const int tid = threadIdx.x;
    const int wav = tid >> 6;
    const int l   = tid & 63;
    const int q   = l >> 4;
    const int c   = l & 15;

    // stage relb (16 KB, L2-hot) into padded LDS: 1024 uint4, 4/thread
    {
        const uint4* src = reinterpret_cast<const uint4*>(relbg);
        #pragma unroll
        for (int i = 0; i < 4; ++i) {
            int u = i * 256 + tid;
            int row = u >> 4, cu = u & 15;
            *reinterpret_cast<uint4*>((char*)Rl + row * 272 + cu * 16) = src[u];
        }
    }

    const int seg = blockIdx.x * 16 + wav * 4 + q;
    const int b   = (seg >= NN) ? 1 : 0;
    unsigned cnt = count[seg];
    if (cnt > CAP) cnt = CAP;
    unsigned pv0 = payload[(size_t)seg * CAP + c];
    unsigned pv1 = payload[(size_t)seg * CAP + 16 + c];

    __syncthreads();  // Rl ready

    const float* nb = node + (size_t)b * NN * CDIM + c * 8;
    const char* rlb = (const char*)Rl + c * 16;

    float acc[8];
    #pragma unroll
    for (int i = 0; i < 8; ++i) acc[i] = 0.f;

    for (unsigned jb = 0; jb < cnt; jb += 4) {
        float w[4]; unsigned p[4];
        #pragma unroll
        for (int k = 0; k < 4; ++k) {
            unsigned j  = jb + k;
            unsigned jc = (j < cnt) ? j : (cnt - 1);
            w[k] = (j < cnt) ? 1.f : 0.f;
            p[k] = __shfl((jc & 16u) ? pv1 : pv0, (int)(jc & 15u), 16);
        }
        float4 ha[4], hb[4]; bf16x8 rv[4];
        #pragma unroll
        for (int k = 0; k < 4; ++k) {
            int s = (int)(p[k] & 0xFFFFu);
            int r = (int)((p[k] >> 16) & 63u);
            const float* h = nb + (size_t)s * CDIM;
            ha[k] = *reinterpret_cast<const float4*>(h);
            hb[k] = *reinterpret_cast<const float4*>(h + 4);
            rv[k] = *reinterpret_cast<const bf16x8*>(rlb + r * 272);
        }
        #pragma unroll
        for (int k = 0; k < 4; ++k) {
            acc[0] = fmaf(w[k], ha[k].x - bf2f((unsigned short)rv[k][0]), acc[0]);
            acc[1] = fmaf(w[k], ha[k].y - bf2f((unsigned short)rv[k][1]), acc[1]);
            acc[2] = fmaf(w[k], ha[k].z - bf2f((unsigned short)rv[k][2]), acc[2]);
            acc[3] = fmaf(w[k], ha[k].w - bf2f((unsigned short)rv[k][3]), acc[3]);
            acc[4] = fmaf(w[k], hb[k].x - bf2f((unsigned short)rv[k][4]), acc[4]);
            acc[5] = fmaf(w[k], hb[k].y - bf2f((unsigned short)rv[k][5]), acc[5]);
            acc[6] = fmaf(w[k], hb[k].z - bf2f((unsigned short)rv[k][6]), acc[6]);
            acc[7] = fmaf(w[k], hb[k].w - bf2f((unsigned short)rv[k][7]), acc[7]);
        }
    }

    // mean + bf16 pack; lane c writes its own 16 B of row (wav*4 + q)
    {
        float inv = 1.f / (float)cnt;  // cnt >= 1 (cover edges)
        int row = wav * 4 + q;
        uint4 pk;
        pk.x = (unsigned)f2bf(acc[0] * inv) | ((unsigned)f2bf(acc[1] * inv) << 16);
        pk.y = (unsigned)f2bf(acc[2] * inv) | ((unsigned)f2bf(acc[3] * inv) << 16);
        pk.z = (unsigned)f2bf(acc[4] * inv) | ((unsigned)f2bf(acc[5] * inv) << 16);
        pk.w = (unsigned)f2bf(acc[6] * inv) | ((unsigned)f2bf(acc[7] * inv) << 16);
        int off = (row * 256 + c * 16) ^ ((row & 7) << 4);
        *reinterpret_cast<uint4*>((char*)Xl + off) = pk;
    }

    __syncthreads();  // x-tile staged

    // A-frags: lane row = c, k = ks*32 + q*8 + j
    bf16x8 afr[4];
    #pragma unroll
    for (int ks = 0; ks < 4; ++ks) {
        int off = (c * 256 + ks * 64 + q * 16) ^ ((c & 7) << 4);
        afr[ks] = *reinterpret_cast<const bf16x8*>((const char*)Xl + off);
    }

    // wave computes cols wav*32 .. wav*32+31 (n = wav*2, wav*2+1)
    size_t rowbase = (size_t)blockIdx.x * 16;
    #pragma unroll
    for (int n2 = 0; n2 < 2; ++n2) {
        int n = wav * 2 + n2;
        f32x4 accv = (f32x4){0.f, 0.f, 0.f, 0.f};
        #pragma unroll
        for (int ks = 0; ks < 4; ++ks) {
            bf16x8 bfr = reinterpret_cast<const bf16x8*>(Wbf)[(n * 4 + ks) * 64 + l];
            accv = __builtin_amdgcn_mfma_f32_16x16x32_bf16(afr[ks], bfr, accv, 0, 0, 0);
        }
        #pragma unroll
        for (int j = 0; j < 4; ++j)
            out[(rowbase + q * 4 + j) * CDIM + n * 16 + c] = accv[j];
    }
}

extern "C" void kernel_launch(void* const* d_in, const int* in_sizes, int n_in,
                              void* d_out, int out_size, void* d_ws, size_t ws_size,
                              hipStream_t stream) {
    const float* node = (const float*)d_in[0];
    const int*   eidx = (const int*)d_in[1];
    const float* rel  = (const float*)d_in[2];
    const float* W    = (const float*)d_in[3];
    float* out = (float*)d_out;

    // ws: count u32[SEGS] @0 (400000 B); payload u32[SEGS*CAP] @400000
    //     (12.8 MB, ends 13200000); Wbf 32 KB @13200000; relb 16 KB @13232768
    unsigned* count   = (unsigned*)d_ws;
    unsigned* payload = (unsigned*)((char*)d_ws + 400000);
    unsigned* Wbf     = (unsigned*)((char*)d_ws + 13200000);
    unsigned* relb    = (unsigned*)((char*)d_ws + 13232768);

    hipMemsetAsync(count, 0, (size_t)SEGS * sizeof(unsigned), stream);

    binscatter_k<<<EBLK + 1, 256, 0, stream>>>(eidx, count, payload, W, Wbf, rel, relb);
    fused_k<<<SEGS / 16, 256, 0, stream>>>(node, relb, count, payload, Wbf, out);
}

// Round 13
// 85.324 us; speedup vs baseline: 1.2389x; 1.0536x over previous
//
#include <hip/hip_runtime.h>

constexpr int BB   = 2;
constexpr int NN   = 50000;
constexpr int EE   = 600000;
constexpr int CDIM = 128;
constexpr int SEGS = BB * NN;   // 100000
constexpr int CAP  = 32;        // max degree = 1 + Poisson(5); P(>=32) ~ 1e-10
constexpr int EBLK = (EE + 255) / 256;             // edge-bin blocks
constexpr int CBLK = (SEGS * CDIM + 8191) / 8192;  // node-cvt blocks (32 f/thr)

typedef __attribute__((ext_vector_type(8))) short bf16x8;
typedef __attribute__((ext_vector_type(4))) float f32x4;

__device__ __forceinline__ unsigned short f2bf(float f) {
    unsigned u = __builtin_bit_cast(unsigned, f);
    return (unsigned short)((u + 0x7FFFu + ((u >> 16) & 1u)) >> 16);  // RNE
}
__device__ __forceinline__ float bf2f(unsigned short v) {
    unsigned u = ((unsigned)v) << 16;
    return __builtin_bit_cast(float, u);
}

// ---------------------------------------------------------------------------
// binscatter_k — three block roles:
//   [0, EBLK):      bin edges: slot=count[seg]++; payload=src|(rel<<16)
//   EBLK:           W -> bf16 MFMA-B-fragment-linear Wbf; rel -> bf16 relb
//   (EBLK, +CBLK]:  node_states f32 -> bf16 row-major nodeb (25.6 MB)
// ---------------------------------------------------------------------------
__global__ __launch_bounds__(256) void binscatter_k(
    const int* __restrict__ eidx, unsigned* __restrict__ count,
    unsigned* __restrict__ payload, const float* __restrict__ W,
    unsigned* __restrict__ Wbf, const float* __restrict__ rel,
    unsigned* __restrict__ relb, const float* __restrict__ node,
    unsigned short* __restrict__ nodeb)
{
    if (blockIdx.x == EBLK) {
        int t = threadIdx.x;
        #pragma unroll
        for (int i = 0; i < 8; ++i) {
            int u = t * 8 + i;          // 16B unit index, 0..2047
            int l = u & 63, f = u >> 6; // f = n*4 + ks
            int c16 = l & 15, q = l >> 4;
            int col = (f >> 2) * 16 + c16;
            int kb  = (f & 3) * 32 + q * 8;
            const float* wp = W + col * CDIM + kb;
            float4 w0 = *reinterpret_cast<const float4*>(wp);
            float4 w1 = *reinterpret_cast<const float4*>(wp + 4);
            uint4 pk;
            pk.x = (unsigned)f2bf(w0.x) | ((unsigned)f2bf(w0.y) << 16);
            pk.y = (unsigned)f2bf(w0.z) | ((unsigned)f2bf(w0.w) << 16);
            pk.z = (unsigned)f2bf(w1.x) | ((unsigned)f2bf(w1.y) << 16);
            pk.w = (unsigned)f2bf(w1.z) | ((unsigned)f2bf(w1.w) << 16);
            reinterpret_cast<uint4*>(Wbf)[u] = pk;
        }
        // rel -> bf16 linear: 1024 uint4 units, 4 per thread
        const float4* rs = reinterpret_cast<const float4*>(rel);
        uint4* rd = reinterpret_cast<uint4*>(relb);
        #pragma unroll
        for (int i = 0; i < 4; ++i) {
            int u = t * 4 + i;          // 0..1023
            float4 a = rs[u * 2], b2 = rs[u * 2 + 1];
            uint4 pk;
            pk.x = (unsigned)f2bf(a.x) | ((unsigned)f2bf(a.y) << 16);
            pk.y = (unsigned)f2bf(a.z) | ((unsigned)f2bf(a.w) << 16);
            pk.z = (unsigned)f2bf(b2.x) | ((unsigned)f2bf(b2.y) << 16);
            pk.w = (unsigned)f2bf(b2.z) | ((unsigned)f2bf(b2.w) << 16);
            rd[u] = pk;
        }
        return;
    }
    if (blockIdx.x > EBLK) {
        // node f32 -> bf16: each thread converts 32 consecutive floats
        int u = (blockIdx.x - EBLK - 1) * 256 + threadIdx.x;   // 32-float unit
        if (u >= SEGS * CDIM / 32) return;
        const float4* src = reinterpret_cast<const float4*>(node) + (size_t)u * 8;
        uint4* dst = reinterpret_cast<uint4*>(nodeb) + (size_t)u * 4;
        #pragma unroll
        for (int i = 0; i < 4; ++i) {
            float4 a = src[i * 2], b2 = src[i * 2 + 1];
            uint4 pk;
            pk.x = (unsigned)f2bf(a.x) | ((unsigned)f2bf(a.y) << 16);
            pk.y = (unsigned)f2bf(a.z) | ((unsigned)f2bf(a.w) << 16);
            pk.z = (unsigned)f2bf(b2.x) | ((unsigned)f2bf(b2.y) << 16);
            pk.w = (unsigned)f2bf(b2.z) | ((unsigned)f2bf(b2.w) << 16);
            dst[i] = pk;
        }
        return;
    }
    int e = blockIdx.x * 256 + threadIdx.x;
    if (e >= EE) return;
    int b = eidx[e];
    int t = eidx[EE + e];
    int s = eidx[2 * EE + e];
    int r = eidx[3 * EE + e];
    int seg = b * NN + t;
    unsigned slot = atomicAdd(count + seg, 1u);
    if (slot < CAP) payload[(size_t)seg * CAP + slot] = (unsigned)s | ((unsigned)r << 16);
}

// ---------------------------------------------------------------------------
// fused_k<NB>: 256 threads = 4 waves; block owns 16 segments (16x128 tile).
// Gather: each 16-lane QUARTER owns one segment (lane c holds dims
// c*8..c*8+7). j-loop unrolled x4 branchless (clamped idx + 0/1 weight):
// 4 independent node row loads in flight. NB=true: node rows are bf16
// (256 B/row, ONE b128 load per lane per edge -> half the L2-fill bytes).
// rel bf16 in LDS, 272 B padded stride. x-row -> Xl bf16 XOR-swizzled;
// mean fused. MFMA: wave w loads 8 B-frags from L2-hot Wbf, computes cols
// w*32..w*32+31, stores f32.
// ---------------------------------------------------------------------------
template<bool NB>
__global__ __launch_bounds__(256) void fused_k(
    const void* __restrict__ nodev, const unsigned* __restrict__ relbg,
    const unsigned* __restrict__ count, const unsigned* __restrict__ payload,
    const unsigned* __restrict__ Wbf, float* __restrict__ out)
{
    __shared__ __align__(16) unsigned short Rl[64 * 136];   // 17408 B, 272B stride
    __shared__ __align__(16) unsigned short Xl[16 * CDIM];  // 4 KB swizzled

    const int tid = threadIdx.x;
    const int wav = tid >> 6;
    const int l   = tid & 63;
    const int q   = l >> 4;
    const int c   = l & 15;

    // stage relb (16 KB, L2-hot) into padded LDS: 1024 uint4, 4/thread
    {
        const uint4* src = reinterpret_cast<const uint4*>(relbg);
        #pragma unroll
        for (int i = 0; i < 4; ++i) {
            int u = i * 256 + tid;
            int row = u >> 4, cu = u & 15;
            *reinterpret_cast<uint4*>((char*)Rl + row * 272 + cu * 16) = src[u];
        }
    }

    const int seg = blockIdx.x * 16 + wav * 4 + q;
    const int b   = (seg >= NN) ? 1 : 0;
    unsigned cnt = count[seg];
    if (cnt > CAP) cnt = CAP;
    unsigned pv0 = payload[(size_t)seg * CAP + c];
    unsigned pv1 = payload[(size_t)seg * CAP + 16 + c];

    __syncthreads();  // Rl ready

    const char* rlb = (const char*)Rl + c * 16;

    float acc[8];
    #pragma unroll
    for (int i = 0; i < 8; ++i) acc[i] = 0.f;

    for (unsigned jb = 0; jb < cnt; jb += 4) {
        float w[4]; unsigned p[4];
        #pragma unroll
        for (int k = 0; k < 4; ++k) {
            unsigned j  = jb + k;
            unsigned jc = (j < cnt) ? j : (cnt - 1);
            w[k] = (j < cnt) ? 1.f : 0.f;
            p[k] = __shfl((jc & 16u) ? pv1 : pv0, (int)(jc & 15u), 16);
        }
        if constexpr (NB) {
            const unsigned short* nb =
                (const unsigned short*)nodev + (size_t)b * NN * CDIM + c * 8;
            bf16x8 hv[4]; bf16x8 rv[4];
            #pragma unroll
            for (int k = 0; k < 4; ++k) {
                int s = (int)(p[k] & 0xFFFFu);
                int r = (int)((p[k] >> 16) & 63u);
                hv[k] = *reinterpret_cast<const bf16x8*>(nb + (size_t)s * CDIM);
                rv[k] = *reinterpret_cast<const bf16x8*>(rlb + r * 272);
            }
            #pragma unroll
            for (int k = 0; k < 4; ++k)
                #pragma unroll
                for (int i = 0; i < 8; ++i)
                    acc[i] = fmaf(w[k],
                        bf2f((unsigned short)hv[k][i]) - bf2f((unsigned short)rv[k][i]),
                        acc[i]);
        } else {
            const float* nb = (const float*)nodev + (size_t)b * NN * CDIM + c * 8;
            float4 ha[4], hb[4]; bf16x8 rv[4];
            #pragma unroll
            for (int k = 0; k < 4; ++k) {
                int s = (int)(p[k] & 0xFFFFu);
                int r = (int)((p[k] >> 16) & 63u);
                const float* h = nb + (size_t)s * CDIM;
                ha[k] = *reinterpret_cast<const float4*>(h);
                hb[k] = *reinterpret_cast<const float4*>(h + 4);
                rv[k] = *reinterpret_cast<const bf16x8*>(rlb + r * 272);
            }
            #pragma unroll
            for (int k = 0; k < 4; ++k) {
                acc[0] = fmaf(w[k], ha[k].x - bf2f((unsigned short)rv[k][0]), acc[0]);
                acc[1] = fmaf(w[k], ha[k].y - bf2f((unsigned short)rv[k][1]), acc[1]);
                acc[2] = fmaf(w[k], ha[k].z - bf2f((unsigned short)rv[k][2]), acc[2]);
                acc[3] = fmaf(w[k], ha[k].w - bf2f((unsigned short)rv[k][3]), acc[3]);
                acc[4] = fmaf(w[k], hb[k].x - bf2f((unsigned short)rv[k][4]), acc[4]);
                acc[5] = fmaf(w[k], hb[k].y - bf2f((unsigned short)rv[k][5]), acc[5]);
                acc[6] = fmaf(w[k], hb[k].z - bf2f((unsigned short)rv[k][6]), acc[6]);
                acc[7] = fmaf(w[k], hb[k].w - bf2f((unsigned short)rv[k][7]), acc[7]);
            }
        }
    }

    // mean + bf16 pack; lane c writes its own 16 B of row (wav*4 + q)
    {
        float inv = 1.f / (float)cnt;  // cnt >= 1 (cover edges)
        int row = wav * 4 + q;
        uint4 pk;
        pk.x = (unsigned)f2bf(acc[0] * inv) | ((unsigned)f2bf(acc[1] * inv) << 16);
        pk.y = (unsigned)f2bf(acc[2] * inv) | ((unsigned)f2bf(acc[3] * inv) << 16);
        pk.z = (unsigned)f2bf(acc[4] * inv) | ((unsigned)f2bf(acc[5] * inv) << 16);
        pk.w = (unsigned)f2bf(acc[6] * inv) | ((unsigned)f2bf(acc[7] * inv) << 16);
        int off = (row * 256 + c * 16) ^ ((row & 7) << 4);
        *reinterpret_cast<uint4*>((char*)Xl + off) = pk;
    }

    __syncthreads();  // x-tile staged

    // A-frags: lane row = c, k = ks*32 + q*8 + j
    bf16x8 afr[4];
    #pragma unroll
    for (int ks = 0; ks < 4; ++ks) {
        int off = (c * 256 + ks * 64 + q * 16) ^ ((c & 7) << 4);
        afr[ks] = *reinterpret_cast<const bf16x8*>((const char*)Xl + off);
    }

    // wave computes cols wav*32 .. wav*32+31 (n = wav*2, wav*2+1)
    size_t rowbase = (size_t)blockIdx.x * 16;
    #pragma unroll
    for (int n2 = 0; n2 < 2; ++n2) {
        int n = wav * 2 + n2;
        f32x4 accv = (f32x4){0.f, 0.f, 0.f, 0.f};
        #pragma unroll
        for (int ks = 0; ks < 4; ++ks) {
            bf16x8 bfr = reinterpret_cast<const bf16x8*>(Wbf)[(n * 4 + ks) * 64 + l];
            accv = __builtin_amdgcn_mfma_f32_16x16x32_bf16(afr[ks], bfr, accv, 0, 0, 0);
        }
        #pragma unroll
        for (int j = 0; j < 4; ++j)
            out[(rowbase + q * 4 + j) * CDIM + n * 16 + c] = accv[j];
    }
}

extern "C" void kernel_launch(void* const* d_in, const int* in_sizes, int n_in,
                              void* d_out, int out_size, void* d_ws, size_t ws_size,
                              hipStream_t stream) {
    const float* node = (const float*)d_in[0];
    const int*   eidx = (const int*)d_in[1];
    const float* rel  = (const float*)d_in[2];
    const float* W    = (const float*)d_in[3];
    float* out = (float*)d_out;

    // ws: count u32[SEGS] @0 (400000); payload u32[SEGS*CAP] @400000
    //     (ends 13200000); Wbf 32 KB @13200000; relb 16 KB @13232768;
    //     nodeb bf16[SEGS*CDIM] @13249152 (ends 38849152)
    unsigned* count   = (unsigned*)d_ws;
    unsigned* payload = (unsigned*)((char*)d_ws + 400000);
    unsigned* Wbf     = (unsigned*)((char*)d_ws + 13200000);
    unsigned* relb    = (unsigned*)((char*)d_ws + 13232768);
    unsigned short* nodeb = (unsigned short*)((char*)d_ws + 13249152);
    const size_t NEED = 13249152ull + (size_t)SEGS * CDIM * 2;
    const bool use_bf = (ws_size >= NEED);

    hipMemsetAsync(count, 0, (size_t)SEGS * sizeof(unsigned), stream);

    int grid = use_bf ? (EBLK + 1 + CBLK) : (EBLK + 1);
    binscatter_k<<<grid, 256, 0, stream>>>(eidx, count, payload, W, Wbf,
                                           rel, relb, node, nodeb);

    if (use_bf)
        fused_k<true><<<SEGS / 16, 256, 0, stream>>>(nodeb, relb, count, payload, Wbf, out);
    else
        fused_k<false><<<SEGS / 16, 256, 0, stream>>>(node, relb, count, payload, Wbf, out);
}

// Round 14
// 77.556 us; speedup vs baseline: 1.3630x; 1.1002x over previous
//
#include <hip/hip_runtime.h>

constexpr int BB   = 2;
constexpr int NN   = 50000;
constexpr int EE   = 600000;
constexpr int CDIM = 128;
constexpr int SEGS = BB * NN;   // 100000
constexpr int CAP  = 32;        // max degree = 1 + Poisson(5); P(>=32) ~ 1e-10
constexpr int EBLK = (EE + 255) / 256;             // 2344 edge blocks
constexpr int CBLK = (SEGS * CDIM + 8191) / 8192;  // 1563 node-cvt blocks
constexpr int GRPS = 782;                          // groups of 5: 3 edge + 2 cvt

typedef __attribute__((ext_vector_type(8))) short bf16x8;
typedef __attribute__((ext_vector_type(4))) float f32x4;

__device__ __forceinline__ unsigned short f2bf(float f) {
    unsigned u = __builtin_bit_cast(unsigned, f);
    return (unsigned short)((u + 0x7FFFu + ((u >> 16) & 1u)) >> 16);  // RNE
}
__device__ __forceinline__ float bf2f(unsigned short v) {
    unsigned u = ((unsigned)v) << 16;
    return __builtin_bit_cast(float, u);
}

// ---------------------------------------------------------------------------
// binscatter_k — roles INTERLEAVED by blockIdx (group of 5 = 3 edge + 2 cvt)
// so latency-bound edge-binning co-schedules with BW-bound node conversion:
//   edge role (eid < EBLK):  slot=count[seg]++; payload=src|(rel<<16)
//   edge role (eid == EBLK): W -> bf16 frag-linear Wbf; rel -> bf16 relb
//   cvt role  (cid < CBLK):  node_states f32 -> bf16 row-major nodeb
// ---------------------------------------------------------------------------
__global__ __launch_bounds__(256) void binscatter_k(
    const int* __restrict__ eidx, unsigned* __restrict__ count,
    unsigned* __restrict__ payload, const float* __restrict__ W,
    unsigned* __restrict__ Wbf, const float* __restrict__ rel,
    unsigned* __restrict__ relb, const float* __restrict__ node,
    unsigned short* __restrict__ nodeb, int do_cvt)
{
    const int grp = blockIdx.x / 5, pos = blockIdx.x % 5;
    const int t = threadIdx.x;

    if (pos >= 3) {
        // ---- node conversion role ----
        if (!do_cvt) return;
        int cid = grp * 2 + (pos - 3);
        if (cid >= CBLK) return;
        int u = cid * 256 + t;             // 32-float unit
        if (u >= SEGS * CDIM / 32) return;
        const float4* src = reinterpret_cast<const float4*>(node) + (size_t)u * 8;
        uint4* dst = reinterpret_cast<uint4*>(nodeb) + (size_t)u * 4;
        #pragma unroll
        for (int i = 0; i < 4; ++i) {
            float4 a = src[i * 2], b2 = src[i * 2 + 1];
            uint4 pk;
            pk.x = (unsigned)f2bf(a.x) | ((unsigned)f2bf(a.y) << 16);
            pk.y = (unsigned)f2bf(a.z) | ((unsigned)f2bf(a.w) << 16);
            pk.z = (unsigned)f2bf(b2.x) | ((unsigned)f2bf(b2.y) << 16);
            pk.w = (unsigned)f2bf(b2.z) | ((unsigned)f2bf(b2.w) << 16);
            dst[i] = pk;
        }
        return;
    }

    int eid = grp * 3 + pos;
    if (eid > EBLK) return;
    if (eid == EBLK) {
        // ---- W + rel conversion role ----
        #pragma unroll
        for (int i = 0; i < 8; ++i) {
            int u = t * 8 + i;          // 16B unit index, 0..2047
            int l = u & 63, f = u >> 6; // f = n*4 + ks
            int c16 = l & 15, q = l >> 4;
            int col = (f >> 2) * 16 + c16;
            int kb  = (f & 3) * 32 + q * 8;
            const float* wp = W + col * CDIM + kb;
            float4 w0 = *reinterpret_cast<const float4*>(wp);
            float4 w1 = *reinterpret_cast<const float4*>(wp + 4);
            uint4 pk;
            pk.x = (unsigned)f2bf(w0.x) | ((unsigned)f2bf(w0.y) << 16);
            pk.y = (unsigned)f2bf(w0.z) | ((unsigned)f2bf(w0.w) << 16);
            pk.z = (unsigned)f2bf(w1.x) | ((unsigned)f2bf(w1.y) << 16);
            pk.w = (unsigned)f2bf(w1.z) | ((unsigned)f2bf(w1.w) << 16);
            reinterpret_cast<uint4*>(Wbf)[u] = pk;
        }
        const float4* rs = reinterpret_cast<const float4*>(rel);
        uint4* rd = reinterpret_cast<uint4*>(relb);
        #pragma unroll
        for (int i = 0; i < 4; ++i) {
            int u = t * 4 + i;          // 0..1023
            float4 a = rs[u * 2], b2 = rs[u * 2 + 1];
            uint4 pk;
            pk.x = (unsigned)f2bf(a.x) | ((unsigned)f2bf(a.y) << 16);
            pk.y = (unsigned)f2bf(a.z) | ((unsigned)f2bf(a.w) << 16);
            pk.z = (unsigned)f2bf(b2.x) | ((unsigned)f2bf(b2.y) << 16);
            pk.w = (unsigned)f2bf(b2.z) | ((unsigned)f2bf(b2.w) << 16);
            rd[u] = pk;
        }
        return;
    }

    // ---- edge-binning role ----
    int e = eid * 256 + t;
    if (e >= EE) return;
    int b = eidx[e];
    int tt = eidx[EE + e];
    int s = eidx[2 * EE + e];
    int r = eidx[3 * EE + e];
    int seg = b * NN + tt;
    unsigned slot = atomicAdd(count + seg, 1u);
    if (slot < CAP) payload[(size_t)seg * CAP + slot] = (unsigned)s | ((unsigned)r << 16);
}

// ---------------------------------------------------------------------------
// fused_k<NB>: 256 threads = 4 waves; block owns 16 segments (16x128 tile).
// Gather: each 16-lane QUARTER owns one segment (lane c holds dims
// c*8..c*8+7). j-loop unrolled x4 branchless (clamped idx + 0/1 weight):
// 4 independent node row loads in flight. NB=true: node rows are bf16
// (256 B/row, ONE b128 load per lane per edge -> half the L2-fill bytes).
// rel bf16 in LDS, 272 B padded stride. x-row -> Xl bf16 XOR-swizzled;
// mean fused. MFMA: wave w loads 8 B-frags from L2-hot Wbf, computes cols
// w*32..w*32+31, stores f32.
// ---------------------------------------------------------------------------
template<bool NB>
__global__ __launch_bounds__(256) void fused_k(
    const void* __restrict__ nodev, const unsigned* __restrict__ relbg,
    const unsigned* __restrict__ count, const unsigned* __restrict__ payload,
    const unsigned* __restrict__ Wbf, float* __restrict__ out)
{
    __shared__ __align__(16) unsigned short Rl[64 * 136];   // 17408 B, 272B stride
    __shared__ __align__(16) unsigned short Xl[16 * CDIM];  // 4 KB swizzled

    const int tid = threadIdx.x;
    const int wav = tid >> 6;
    const int l   = tid & 63;
    const int q   = l >> 4;
    const int c   = l & 15;

    // stage relb (16 KB, L2-hot) into padded LDS: 1024 uint4, 4/thread
    {
        const uint4* src = reinterpret_cast<const uint4*>(relbg);
        #pragma unroll
        for (int i = 0; i < 4; ++i) {
            int u = i * 256 + tid;
            int row = u >> 4, cu = u & 15;
            *reinterpret_cast<uint4*>((char*)Rl + row * 272 + cu * 16) = src[u];
        }
    }

    const int seg = blockIdx.x * 16 + wav * 4 + q;
    const int b   = (seg >= NN) ? 1 : 0;
    unsigned cnt = count[seg];
    if (cnt > CAP) cnt = CAP;
    unsigned pv0 = payload[(size_t)seg * CAP + c];
    unsigned pv1 = payload[(size_t)seg * CAP + 16 + c];

    __syncthreads();  // Rl ready

    const char* rlb = (const char*)Rl + c * 16;

    float acc[8];
    #pragma unroll
    for (int i = 0; i < 8; ++i) acc[i] = 0.f;

    for (unsigned jb = 0; jb < cnt; jb += 4) {
        float w[4]; unsigned p[4];
        #pragma unroll
        for (int k = 0; k < 4; ++k) {
            unsigned j  = jb + k;
            unsigned jc = (j < cnt) ? j : (cnt - 1);
            w[k] = (j < cnt) ? 1.f : 0.f;
            p[k] = __shfl((jc & 16u) ? pv1 : pv0, (int)(jc & 15u), 16);
        }
        if constexpr (NB) {
            const unsigned short* nb =
                (const unsigned short*)nodev + (size_t)b * NN * CDIM + c * 8;
            bf16x8 hv[4]; bf16x8 rv[4];
            #pragma unroll
            for (int k = 0; k < 4; ++k) {
                int s = (int)(p[k] & 0xFFFFu);
                int r = (int)((p[k] >> 16) & 63u);
                hv[k] = *reinterpret_cast<const bf16x8*>(nb + (size_t)s * CDIM);
                rv[k] = *reinterpret_cast<const bf16x8*>(rlb + r * 272);
            }
            #pragma unroll
            for (int k = 0; k < 4; ++k)
                #pragma unroll
                for (int i = 0; i < 8; ++i)
                    acc[i] = fmaf(w[k],
                        bf2f((unsigned short)hv[k][i]) - bf2f((unsigned short)rv[k][i]),
                        acc[i]);
        } else {
            const float* nb = (const float*)nodev + (size_t)b * NN * CDIM + c * 8;
            float4 ha[4], hb[4]; bf16x8 rv[4];
            #pragma unroll
            for (int k = 0; k < 4; ++k) {
                int s = (int)(p[k] & 0xFFFFu);
                int r = (int)((p[k] >> 16) & 63u);
                const float* h = nb + (size_t)s * CDIM;
                ha[k] = *reinterpret_cast<const float4*>(h);
                hb[k] = *reinterpret_cast<const float4*>(h + 4);
                rv[k] = *reinterpret_cast<const bf16x8*>(rlb + r * 272);
            }
            #pragma unroll
            for (int k = 0; k < 4; ++k) {
                acc[0] = fmaf(w[k], ha[k].x - bf2f((unsigned short)rv[k][0]), acc[0]);
                acc[1] = fmaf(w[k], ha[k].y - bf2f((unsigned short)rv[k][1]), acc[1]);
                acc[2] = fmaf(w[k], ha[k].z - bf2f((unsigned short)rv[k][2]), acc[2]);
                acc[3] = fmaf(w[k], ha[k].w - bf2f((unsigned short)rv[k][3]), acc[3]);
                acc[4] = fmaf(w[k], hb[k].x - bf2f((unsigned short)rv[k][4]), acc[4]);
                acc[5] = fmaf(w[k], hb[k].y - bf2f((unsigned short)rv[k][5]), acc[5]);
                acc[6] = fmaf(w[k], hb[k].z - bf2f((unsigned short)rv[k][6]), acc[6]);
                acc[7] = fmaf(w[k], hb[k].w - bf2f((unsigned short)rv[k][7]), acc[7]);
            }
        }
    }

    // mean + bf16 pack; lane c writes its own 16 B of row (wav*4 + q)
    {
        float inv = 1.f / (float)cnt;  // cnt >= 1 (cover edges)
        int row = wav * 4 + q;
        uint4 pk;
        pk.x = (unsigned)f2bf(acc[0] * inv) | ((unsigned)f2bf(acc[1] * inv) << 16);
        pk.y = (unsigned)f2bf(acc[2] * inv) | ((unsigned)f2bf(acc[3] * inv) << 16);
        pk.z = (unsigned)f2bf(acc[4] * inv) | ((unsigned)f2bf(acc[5] * inv) << 16);
        pk.w = (unsigned)f2bf(acc[6] * inv) | ((unsigned)f2bf(acc[7] * inv) << 16);
        int off = (row * 256 + c * 16) ^ ((row & 7) << 4);
        *reinterpret_cast<uint4*>((char*)Xl + off) = pk;
    }

    __syncthreads();  // x-tile staged

    // A-frags: lane row = c, k = ks*32 + q*8 + j
    bf16x8 afr[4];
    #pragma unroll
    for (int ks = 0; ks < 4; ++ks) {
        int off = (c * 256 + ks * 64 + q * 16) ^ ((c & 7) << 4);
        afr[ks] = *reinterpret_cast<const bf16x8*>((const char*)Xl + off);
    }

    // wave computes cols wav*32 .. wav*32+31 (n = wav*2, wav*2+1)
    size_t rowbase = (size_t)blockIdx.x * 16;
    #pragma unroll
    for (int n2 = 0; n2 < 2; ++n2) {
        int n = wav * 2 + n2;
        f32x4 accv = (f32x4){0.f, 0.f, 0.f, 0.f};
        #pragma unroll
        for (int ks = 0; ks < 4; ++ks) {
            bf16x8 bfr = reinterpret_cast<const bf16x8*>(Wbf)[(n * 4 + ks) * 64 + l];
            accv = __builtin_amdgcn_mfma_f32_16x16x32_bf16(afr[ks], bfr, accv, 0, 0, 0);
        }
        #pragma unroll
        for (int j = 0; j < 4; ++j)
            out[(rowbase + q * 4 + j) * CDIM + n * 16 + c] = accv[j];
    }
}

extern "C" void kernel_launch(void* const* d_in, const int* in_sizes, int n_in,
                              void* d_out, int out_size, void* d_ws, size_t ws_size,
                              hipStream_t stream) {
    const float* node = (const float*)d_in[0];
    const int*   eidx = (const int*)d_in[1];
    const float* rel  = (const float*)d_in[2];
    const float* W    = (const float*)d_in[3];
    float* out = (float*)d_out;

    // ws: count u32[SEGS] @0 (400000); payload u32[SEGS*CAP] @400000
    //     (ends 13200000); Wbf 32 KB @13200000; relb 16 KB @13232768;
    //     nodeb bf16[SEGS*CDIM] @13249152 (ends 38849152)
    unsigned* count   = (unsigned*)d_ws;
    unsigned* payload = (unsigned*)((char*)d_ws + 400000);
    unsigned* Wbf     = (unsigned*)((char*)d_ws + 13200000);
    unsigned* relb    = (unsigned*)((char*)d_ws + 13232768);
    unsigned short* nodeb = (unsigned short*)((char*)d_ws + 13249152);
    const size_t NEED = 13249152ull + (size_t)SEGS * CDIM * 2;
    const bool use_bf = (ws_size >= NEED);

    hipMemsetAsync(count, 0, (size_t)SEGS * sizeof(unsigned), stream);

    binscatter_k<<<GRPS * 5, 256, 0, stream>>>(eidx, count, payload, W, Wbf,
                                               rel, relb, node, nodeb,
                                               use_bf ? 1 : 0);

    if (use_bf)
        fused_k<true><<<SEGS / 16, 256, 0, stream>>>(nodeb, relb, count, payload, Wbf, out);
    else
        fused_k<false><<<SEGS / 16, 256, 0, stream>>>(node, relb, count, payload, Wbf, out);
}

// Round 15
// 76.734 us; speedup vs baseline: 1.3776x; 1.0107x over previous
//
#include <hip/hip_runtime.h>

constexpr int BB   = 2;
constexpr int NN   = 50000;
constexpr int EE   = 600000;
constexpr int CDIM = 128;
constexpr int SEGS = BB * NN;   // 100000
constexpr int CAP  = 32;        // max degree = 1 + Poisson(5); P(>=32) ~ 1e-10
constexpr int EBLK = (EE + 255) / 256;             // 2344 edge blocks
constexpr int CBLK = (SEGS * CDIM + 8191) / 8192;  // 1563 node-cvt blocks
constexpr int GRPS = 782;                          // groups of 5: 3 edge + 2 cvt
constexpr int NUNITS = SEGS * CDIM / 8;            // 1.6M 8-float units

typedef __attribute__((ext_vector_type(8))) short bf16x8;
typedef __attribute__((ext_vector_type(4))) float f32x4;

__device__ __forceinline__ unsigned short f2bf(float f) {
    unsigned u = __builtin_bit_cast(unsigned, f);
    return (unsigned short)((u + 0x7FFFu + ((u >> 16) & 1u)) >> 16);  // RNE
}
__device__ __forceinline__ float bf2f(unsigned short v) {
    unsigned u = ((unsigned)v) << 16;
    return __builtin_bit_cast(float, u);
}

// ---------------------------------------------------------------------------
// binscatter_k — roles INTERLEAVED by blockIdx (group of 5 = 3 edge + 2 cvt):
//   edge role (eid < EBLK):  slot=count[seg]++; payload=src|(rel<<16)
//   edge role (eid == EBLK): W -> bf16 frag-linear Wbf; rel -> bf16 relb
//   cvt role  (cid < CBLK):  node f32 -> bf16, LANE-COALESCED: unit v =
//     cid*1024 + i*256 + tid (8 floats/unit) -> every load instr reads a
//     contiguous 2 KB wave span, every store writes contiguous 1 KB. [R15]
// ---------------------------------------------------------------------------
__global__ __launch_bounds__(256) void binscatter_k(
    const int* __restrict__ eidx, unsigned* __restrict__ count,
    unsigned* __restrict__ payload, const float* __restrict__ W,
    unsigned* __restrict__ Wbf, const float* __restrict__ rel,
    unsigned* __restrict__ relb, const float* __restrict__ node,
    unsigned short* __restrict__ nodeb, int do_cvt)
{
    const int grp = blockIdx.x / 5, pos = blockIdx.x % 5;
    const int t = threadIdx.x;

    if (pos >= 3) {
        // ---- node conversion role (coalesced) ----
        if (!do_cvt) return;
        int cid = grp * 2 + (pos - 3);
        if (cid >= CBLK) return;
        const float4* src = reinterpret_cast<const float4*>(node);
        uint4* dst = reinterpret_cast<uint4*>(nodeb);
        #pragma unroll
        for (int i = 0; i < 4; ++i) {
            int v = cid * 1024 + i * 256 + t;   // 8-float unit index
            if (v < NUNITS) {
                float4 a = src[v * 2], b2 = src[v * 2 + 1];
                uint4 pk;
                pk.x = (unsigned)f2bf(a.x) | ((unsigned)f2bf(a.y) << 16);
                pk.y = (unsigned)f2bf(a.z) | ((unsigned)f2bf(a.w) << 16);
                pk.z = (unsigned)f2bf(b2.x) | ((unsigned)f2bf(b2.y) << 16);
                pk.w = (unsigned)f2bf(b2.z) | ((unsigned)f2bf(b2.w) << 16);
                dst[v] = pk;
            }
        }
        return;
    }

    int eid = grp * 3 + pos;
    if (eid > EBLK) return;
    if (eid == EBLK) {
        // ---- W + rel conversion role ----
        #pragma unroll
        for (int i = 0; i < 8; ++i) {
            int u = t * 8 + i;          // 16B unit index, 0..2047
            int l = u & 63, f = u >> 6; // f = n*4 + ks
            int c16 = l & 15, q = l >> 4;
            int col = (f >> 2) * 16 + c16;
            int kb  = (f & 3) * 32 + q * 8;
            const float* wp = W + col * CDIM + kb;
            float4 w0 = *reinterpret_cast<const float4*>(wp);
            float4 w1 = *reinterpret_cast<const float4*>(wp + 4);
            uint4 pk;
            pk.x = (unsigned)f2bf(w0.x) | ((unsigned)f2bf(w0.y) << 16);
            pk.y = (unsigned)f2bf(w0.z) | ((unsigned)f2bf(w0.w) << 16);
            pk.z = (unsigned)f2bf(w1.x) | ((unsigned)f2bf(w1.y) << 16);
            pk.w = (unsigned)f2bf(w1.z) | ((unsigned)f2bf(w1.w) << 16);
            reinterpret_cast<uint4*>(Wbf)[u] = pk;
        }
        const float4* rs = reinterpret_cast<const float4*>(rel);
        uint4* rd = reinterpret_cast<uint4*>(relb);
        #pragma unroll
        for (int i = 0; i < 4; ++i) {
            int u = t * 4 + i;          // 0..1023
            float4 a = rs[u * 2], b2 = rs[u * 2 + 1];
            uint4 pk;
            pk.x = (unsigned)f2bf(a.x) | ((unsigned)f2bf(a.y) << 16);
            pk.y = (unsigned)f2bf(a.z) | ((unsigned)f2bf(a.w) << 16);
            pk.z = (unsigned)f2bf(b2.x) | ((unsigned)f2bf(b2.y) << 16);
            pk.w = (unsigned)f2bf(b2.z) | ((unsigned)f2bf(b2.w) << 16);
            rd[u] = pk;
        }
        return;
    }

    // ---- edge-binning role ----
    int e = eid * 256 + t;
    if (e >= EE) return;
    int b = eidx[e];
    int tt = eidx[EE + e];
    int s = eidx[2 * EE + e];
    int r = eidx[3 * EE + e];
    int seg = b * NN + tt;
    unsigned slot = atomicAdd(count + seg, 1u);
    if (slot < CAP) payload[(size_t)seg * CAP + slot] = (unsigned)s | ((unsigned)r << 16);
}

// ---------------------------------------------------------------------------
// fused_k<NB>: 256 threads = 4 waves; block owns 16 segments (16x128 tile).
// Gather: each 16-lane QUARTER owns one segment (lane c holds dims
// c*8..c*8+7). j-loop unrolled x4 branchless (clamped idx + 0/1 weight):
// 4 independent node row loads in flight. NB=true: node rows are bf16
// (256 B/row, ONE b128 load per lane per edge -> half the L2-fill bytes).
// rel bf16 in LDS, 272 B padded stride. x-row -> Xl bf16 XOR-swizzled;
// mean fused. MFMA: wave w loads 8 B-frags from L2-hot Wbf, computes cols
// w*32..w*32+31, stores f32.
// ---------------------------------------------------------------------------
template<bool NB>
__global__ __launch_bounds__(256) void fused_k(
    const void* __restrict__ nodev, const unsigned* __restrict__ relbg,
    const unsigned* __restrict__ count, const unsigned* __restrict__ payload,
    const unsigned* __restrict__ Wbf, float* __restrict__ out)
{
    __shared__ __align__(16) unsigned short Rl[64 * 136];   // 17408 B, 272B stride
    __shared__ __align__(16) unsigned short Xl[16 * CDIM];  // 4 KB swizzled

    const int tid = threadIdx.x;
    const int wav = tid >> 6;
    const int l   = tid & 63;
    const int q   = l >> 4;
    const int c   = l & 15;

    // stage relb (16 KB, L2-hot) into padded LDS: 1024 uint4, 4/thread
    {
        const uint4* src = reinterpret_cast<const uint4*>(relbg);
        #pragma unroll
        for (int i = 0; i < 4; ++i) {
            int u = i * 256 + tid;
            int row = u >> 4, cu = u & 15;
            *reinterpret_cast<uint4*>((char*)Rl + row * 272 + cu * 16) = src[u];
        }
    }

    const int seg = blockIdx.x * 16 + wav * 4 + q;
    const int b   = (seg >= NN) ? 1 : 0;
    unsigned cnt = count[seg];
    if (cnt > CAP) cnt = CAP;
    unsigned pv0 = payload[(size_t)seg * CAP + c];
    unsigned pv1 = payload[(size_t)seg * CAP + 16 + c];

    __syncthreads();  // Rl ready

    const char* rlb = (const char*)Rl + c * 16;

    float acc[8];
    #pragma unroll
    for (int i = 0; i < 8; ++i) acc[i] = 0.f;

    for (unsigned jb = 0; jb < cnt; jb += 4) {
        float w[4]; unsigned p[4];
        #pragma unroll
        for (int k = 0; k < 4; ++k) {
            unsigned j  = jb + k;
            unsigned jc = (j < cnt) ? j : (cnt - 1);
            w[k] = (j < cnt) ? 1.f : 0.f;
            p[k] = __shfl((jc & 16u) ? pv1 : pv0, (int)(jc & 15u), 16);
        }
        if constexpr (NB) {
            const unsigned short* nb =
                (const unsigned short*)nodev + (size_t)b * NN * CDIM + c * 8;
            bf16x8 hv[4]; bf16x8 rv[4];
            #pragma unroll
            for (int k = 0; k < 4; ++k) {
                int s = (int)(p[k] & 0xFFFFu);
                int r = (int)((p[k] >> 16) & 63u);
                hv[k] = *reinterpret_cast<const bf16x8*>(nb + (size_t)s * CDIM);
                rv[k] = *reinterpret_cast<const bf16x8*>(rlb + r * 272);
            }
            #pragma unroll
            for (int k = 0; k < 4; ++k)
                #pragma unroll
                for (int i = 0; i < 8; ++i)
                    acc[i] = fmaf(w[k],
                        bf2f((unsigned short)hv[k][i]) - bf2f((unsigned short)rv[k][i]),
                        acc[i]);
        } else {
            const float* nb = (const float*)nodev + (size_t)b * NN * CDIM + c * 8;
            float4 ha[4], hb[4]; bf16x8 rv[4];
            #pragma unroll
            for (int k = 0; k < 4; ++k) {
                int s = (int)(p[k] & 0xFFFFu);
                int r = (int)((p[k] >> 16) & 63u);
                const float* h = nb + (size_t)s * CDIM;
                ha[k] = *reinterpret_cast<const float4*>(h);
                hb[k] = *reinterpret_cast<const float4*>(h + 4);
                rv[k] = *reinterpret_cast<const bf16x8*>(rlb + r * 272);
            }
            #pragma unroll
            for (int k = 0; k < 4; ++k) {
                acc[0] = fmaf(w[k], ha[k].x - bf2f((unsigned short)rv[k][0]), acc[0]);
                acc[1] = fmaf(w[k], ha[k].y - bf2f((unsigned short)rv[k][1]), acc[1]);
                acc[2] = fmaf(w[k], ha[k].z - bf2f((unsigned short)rv[k][2]), acc[2]);
                acc[3] = fmaf(w[k], ha[k].w - bf2f((unsigned short)rv[k][3]), acc[3]);
                acc[4] = fmaf(w[k], hb[k].x - bf2f((unsigned short)rv[k][4]), acc[4]);
                acc[5] = fmaf(w[k], hb[k].y - bf2f((unsigned short)rv[k][5]), acc[5]);
                acc[6] = fmaf(w[k], hb[k].z - bf2f((unsigned short)rv[k][6]), acc[6]);
                acc[7] = fmaf(w[k], hb[k].w - bf2f((unsigned short)rv[k][7]), acc[7]);
            }
        }
    }

    // mean + bf16 pack; lane c writes its own 16 B of row (wav*4 + q)
    {
        float inv = 1.f / (float)cnt;  // cnt >= 1 (cover edges)
        int row = wav * 4 + q;
        uint4 pk;
        pk.x = (unsigned)f2bf(acc[0] * inv) | ((unsigned)f2bf(acc[1] * inv) << 16);
        pk.y = (unsigned)f2bf(acc[2] * inv) | ((unsigned)f2bf(acc[3] * inv) << 16);
        pk.z = (unsigned)f2bf(acc[4] * inv) | ((unsigned)f2bf(acc[5] * inv) << 16);
        pk.w = (unsigned)f2bf(acc[6] * inv) | ((unsigned)f2bf(acc[7] * inv) << 16);
        int off = (row * 256 + c * 16) ^ ((row & 7) << 4);
        *reinterpret_cast<uint4*>((char*)Xl + off) = pk;
    }

    __syncthreads();  // x-tile staged

    // A-frags: lane row = c, k = ks*32 + q*8 + j
    bf16x8 afr[4];
    #pragma unroll
    for (int ks = 0; ks < 4; ++ks) {
        int off = (c * 256 + ks * 64 + q * 16) ^ ((c & 7) << 4);
        afr[ks] = *reinterpret_cast<const bf16x8*>((const char*)Xl + off);
    }

    // wave computes cols wav*32 .. wav*32+31 (n = wav*2, wav*2+1)
    size_t rowbase = (size_t)blockIdx.x * 16;
    #pragma unroll
    for (int n2 = 0; n2 < 2; ++n2) {
        int n = wav * 2 + n2;
        f32x4 accv = (f32x4){0.f, 0.f, 0.f, 0.f};
        #pragma unroll
        for (int ks = 0; ks < 4; ++ks) {
            bf16x8 bfr = reinterpret_cast<const bf16x8*>(Wbf)[(n * 4 + ks) * 64 + l];
            accv = __builtin_amdgcn_mfma_f32_16x16x32_bf16(afr[ks], bfr, accv, 0, 0, 0);
        }
        #pragma unroll
        for (int j = 0; j < 4; ++j)
            out[(rowbase + q * 4 + j) * CDIM + n * 16 + c] = accv[j];
    }
}

extern "C" void kernel_launch(void* const* d_in, const int* in_sizes, int n_in,
                              void* d_out, int out_size, void* d_ws, size_t ws_size,
                              hipStream_t stream) {
    const float* node = (const float*)d_in[0];
    const int*   eidx = (const int*)d_in[1];
    const float* rel  = (const float*)d_in[2];
    const float* W    = (const float*)d_in[3];
    float* out = (float*)d_out;

    // ws: count u32[SEGS] @0 (400000); payload u32[SEGS*CAP] @400000
    //     (ends 13200000); Wbf 32 KB @13200000; relb 16 KB @13232768;
    //     nodeb bf16[SEGS*CDIM] @13249152 (ends 38849152)
    unsigned* count   = (unsigned*)d_ws;
    unsigned* payload = (unsigned*)((char*)d_ws + 400000);
    unsigned* Wbf     = (unsigned*)((char*)d_ws + 13200000);
    unsigned* relb    = (unsigned*)((char*)d_ws + 13232768);
    unsigned short* nodeb = (unsigned short*)((char*)d_ws + 13249152);
    const size_t NEED = 13249152ull + (size_t)SEGS * CDIM * 2;
    const bool use_bf = (ws_size >= NEED);

    hipMemsetAsync(count, 0, (size_t)SEGS * sizeof(unsigned), stream);

    binscatter_k<<<GRPS * 5, 256, 0, stream>>>(eidx, count, payload, W, Wbf,
                                               rel, relb, node, nodeb,
                                               use_bf ? 1 : 0);

    if (use_bf)
        fused_k<true><<<SEGS / 16, 256, 0, stream>>>(nodeb, relb, count, payload, Wbf, out);
    else
        fused_k<false><<<SEGS / 16, 256, 0, stream>>>(node, relb, count, payload, Wbf, out);
}

// Round 16
// 73.439 us; speedup vs baseline: 1.4394x; 1.0449x over previous
//
#include <hip/hip_runtime.h>

constexpr int BB   = 2;
constexpr int NN   = 50000;
constexpr int EE   = 600000;
constexpr int CDIM = 128;
constexpr int SEGS = BB * NN;   // 100000
constexpr int CAP  = 32;        // max degree = 1 + Poisson(5); P(>=32) ~ 1e-10
constexpr int NUNITS = SEGS * CDIM / 8;            // 1.6M 8-float units
constexpr int EB4  = (EE + 1023) / 1024;           // 586 edge blocks (4 edges/thr)
constexpr int CV12 = (NUNITS + 3071) / 3072;       // 521 cvt blocks (12 units/thr)

typedef __attribute__((ext_vector_type(8))) short bf16x8;
typedef __attribute__((ext_vector_type(4))) float f32x4;

__device__ __forceinline__ unsigned short f2bf(float f) {
    unsigned u = __builtin_bit_cast(unsigned, f);
    return (unsigned short)((u + 0x7FFFu + ((u >> 16) & 1u)) >> 16);  // RNE
}
__device__ __forceinline__ float bf2f(unsigned short v) {
    unsigned u = ((unsigned)v) << 16;
    return __builtin_bit_cast(float, u);
}

// ---------------------------------------------------------------------------
// binscatter_k — 1:1 interleave (even block = edge role, odd = cvt role),
// each role internally ILP'd so per-thread latency chains overlap:
//   edge role (eid < EB4):  4 edges/thread -- hoisted clamped eidx loads,
//     then 4 INDEPENDENT atomicAdd->payload-store chains in flight.
//   edge role (eid == EB4): W -> bf16 frag-linear Wbf; rel -> bf16 relb
//   cvt role  (cid < CV12): 12 coalesced 8-float units/thread, f32->bf16.
// ---------------------------------------------------------------------------
__global__ __launch_bounds__(256) void binscatter_k(
    const int* __restrict__ eidx, unsigned* __restrict__ count,
    unsigned* __restrict__ payload, const float* __restrict__ W,
    unsigned* __restrict__ Wbf, const float* __restrict__ rel,
    unsigned* __restrict__ relb, const float* __restrict__ node,
    unsigned short* __restrict__ nodeb, int do_cvt)
{
    const int t = threadIdx.x;

    if (blockIdx.x & 1) {
        // ---- node conversion role: 12 independent coalesced streams ----
        if (!do_cvt) return;
        int cid = blockIdx.x >> 1;
        if (cid >= CV12) return;
        const float4* src = reinterpret_cast<const float4*>(node);
        uint4* dst = reinterpret_cast<uint4*>(nodeb);
        #pragma unroll
        for (int i = 0; i < 12; ++i) {
            int v = cid * 3072 + i * 256 + t;   // 8-float unit index
            if (v < NUNITS) {
                float4 a = src[v * 2], b2 = src[v * 2 + 1];
                uint4 pk;
                pk.x = (unsigned)f2bf(a.x) | ((unsigned)f2bf(a.y) << 16);
                pk.y = (unsigned)f2bf(a.z) | ((unsigned)f2bf(a.w) << 16);
                pk.z = (unsigned)f2bf(b2.x) | ((unsigned)f2bf(b2.y) << 16);
                pk.w = (unsigned)f2bf(b2.z) | ((unsigned)f2bf(b2.w) << 16);
                dst[v] = pk;
            }
        }
        return;
    }

    int eid = blockIdx.x >> 1;
    if (eid == EB4) {
        // ---- W + rel conversion role ----
        #pragma unroll
        for (int i = 0; i < 8; ++i) {
            int u = t * 8 + i;          // 16B unit index, 0..2047
            int l = u & 63, f = u >> 6; // f = n*4 + ks
            int c16 = l & 15, q = l >> 4;
            int col = (f >> 2) * 16 + c16;
            int kb  = (f & 3) * 32 + q * 8;
            const float* wp = W + col * CDIM + kb;
            float4 w0 = *reinterpret_cast<const float4*>(wp);
            float4 w1 = *reinterpret_cast<const float4*>(wp + 4);
            uint4 pk;
            pk.x = (unsigned)f2bf(w0.x) | ((unsigned)f2bf(w0.y) << 16);
            pk.y = (unsigned)f2bf(w0.z) | ((unsigned)f2bf(w0.w) << 16);
            pk.z = (unsigned)f2bf(w1.x) | ((unsigned)f2bf(w1.y) << 16);
            pk.w = (unsigned)f2bf(w1.z) | ((unsigned)f2bf(w1.w) << 16);
            reinterpret_cast<uint4*>(Wbf)[u] = pk;
        }
        const float4* rs = reinterpret_cast<const float4*>(rel);
        uint4* rd = reinterpret_cast<uint4*>(relb);
        #pragma unroll
        for (int i = 0; i < 4; ++i) {
            int u = t * 4 + i;          // 0..1023
            float4 a = rs[u * 2], b2 = rs[u * 2 + 1];
            uint4 pk;
            pk.x = (unsigned)f2bf(a.x) | ((unsigned)f2bf(a.y) << 16);
            pk.y = (unsigned)f2bf(a.z) | ((unsigned)f2bf(a.w) << 16);
            pk.z = (unsigned)f2bf(b2.x) | ((unsigned)f2bf(b2.y) << 16);
            pk.w = (unsigned)f2bf(b2.z) | ((unsigned)f2bf(b2.w) << 16);
            rd[u] = pk;
        }
        return;
    }

    // ---- edge-binning role: 4 edges/thread, independent chains ----
    int bb[4], tt[4], ss[4], rr[4]; bool ok[4];
    #pragma unroll
    for (int i = 0; i < 4; ++i) {
        int e  = eid * 1024 + i * 256 + t;
        ok[i]  = (e < EE);
        int ec = ok[i] ? e : (EE - 1);
        bb[i] = eidx[ec];
        tt[i] = eidx[EE + ec];
        ss[i] = eidx[2 * EE + ec];
        rr[i] = eidx[3 * EE + ec];
    }
    #pragma unroll
    for (int i = 0; i < 4; ++i) {
        if (ok[i]) {
            int seg = bb[i] * NN + tt[i];
            unsigned slot = atomicAdd(count + seg, 1u);
            if (slot < CAP)
                payload[(size_t)seg * CAP + slot] =
                    (unsigned)ss[i] | ((unsigned)rr[i] << 16);
        }
    }
}

// ---------------------------------------------------------------------------
// fused_k<NB>: 256 threads = 4 waves; block owns 16 segments (16x128 tile).
// Gather: each 16-lane QUARTER owns one segment (lane c holds dims
// c*8..c*8+7). j-loop unrolled x4 branchless (clamped idx + 0/1 weight):
// 4 independent node row loads in flight. NB=true: node rows are bf16
// (256 B/row). rel bf16 in LDS, 272 B padded stride. x-row -> Xl bf16
// XOR-swizzled; mean fused. MFMA: wave w loads 8 B-frags from L2-hot Wbf,
// computes cols w*32..w*32+31, stores f32.
// ---------------------------------------------------------------------------
template<bool NB>
__global__ __launch_bounds__(256) void fused_k(
    const void* __restrict__ nodev, const unsigned* __restrict__ relbg,
    const unsigned* __restrict__ count, const unsigned* __restrict__ payload,
    const unsigned* __restrict__ Wbf, float* __restrict__ out)
{
    __shared__ __align__(16) unsigned short Rl[64 * 136];   // 17408 B, 272B stride
    __shared__ __align__(16) unsigned short Xl[16 * CDIM];  // 4 KB swizzled

    const int tid = threadIdx.x;
    const int wav = tid >> 6;
    const int l   = tid & 63;
    const int q   = l >> 4;
    const int c   = l & 15;

    // stage relb (16 KB, L2-hot) into padded LDS: 1024 uint4, 4/thread
    {
        const uint4* src = reinterpret_cast<const uint4*>(relbg);
        #pragma unroll
        for (int i = 0; i < 4; ++i) {
            int u = i * 256 + tid;
            int row = u >> 4, cu = u & 15;
            *reinterpret_cast<uint4*>((char*)Rl + row * 272 + cu * 16) = src[u];
        }
    }

    const int seg = blockIdx.x * 16 + wav * 4 + q;
    const int b   = (seg >= NN) ? 1 : 0;
    unsigned cnt = count[seg];
    if (cnt > CAP) cnt = CAP;
    unsigned pv0 = payload[(size_t)seg * CAP + c];
    unsigned pv1 = payload[(size_t)seg * CAP + 16 + c];

    __syncthreads();  // Rl ready

    const char* rlb = (const char*)Rl + c * 16;

    float acc[8];
    #pragma unroll
    for (int i = 0; i < 8; ++i) acc[i] = 0.f;

    for (unsigned jb = 0; jb < cnt; jb += 4) {
        float w[4]; unsigned p[4];
        #pragma unroll
        for (int k = 0; k < 4; ++k) {
            unsigned j  = jb + k;
            unsigned jc = (j < cnt) ? j : (cnt - 1);
            w[k] = (j < cnt) ? 1.f : 0.f;
            p[k] = __shfl((jc & 16u) ? pv1 : pv0, (int)(jc & 15u), 16);
        }
        if constexpr (NB) {
            const unsigned short* nb =
                (const unsigned short*)nodev + (size_t)b * NN * CDIM + c * 8;
            bf16x8 hv[4]; bf16x8 rv[4];
            #pragma unroll
            for (int k = 0; k < 4; ++k) {
                int s = (int)(p[k] & 0xFFFFu);
                int r = (int)((p[k] >> 16) & 63u);
                hv[k] = *reinterpret_cast<const bf16x8*>(nb + (size_t)s * CDIM);
                rv[k] = *reinterpret_cast<const bf16x8*>(rlb + r * 272);
            }
            #pragma unroll
            for (int k = 0; k < 4; ++k)
                #pragma unroll
                for (int i = 0; i < 8; ++i)
                    acc[i] = fmaf(w[k],
                        bf2f((unsigned short)hv[k][i]) - bf2f((unsigned short)rv[k][i]),
                        acc[i]);
        } else {
            const float* nb = (const float*)nodev + (size_t)b * NN * CDIM + c * 8;
            float4 ha[4], hb[4]; bf16x8 rv[4];
            #pragma unroll
            for (int k = 0; k < 4; ++k) {
                int s = (int)(p[k] & 0xFFFFu);
                int r = (int)((p[k] >> 16) & 63u);
                const float* h = nb + (size_t)s * CDIM;
                ha[k] = *reinterpret_cast<const float4*>(h);
                hb[k] = *reinterpret_cast<const float4*>(h + 4);
                rv[k] = *reinterpret_cast<const bf16x8*>(rlb + r * 272);
            }
            #pragma unroll
            for (int k = 0; k < 4; ++k) {
                acc[0] = fmaf(w[k], ha[k].x - bf2f((unsigned short)rv[k][0]), acc[0]);
                acc[1] = fmaf(w[k], ha[k].y - bf2f((unsigned short)rv[k][1]), acc[1]);
                acc[2] = fmaf(w[k], ha[k].z - bf2f((unsigned short)rv[k][2]), acc[2]);
                acc[3] = fmaf(w[k], ha[k].w - bf2f((unsigned short)rv[k][3]), acc[3]);
                acc[4] = fmaf(w[k], hb[k].x - bf2f((unsigned short)rv[k][4]), acc[4]);
                acc[5] = fmaf(w[k], hb[k].y - bf2f((unsigned short)rv[k][5]), acc[5]);
                acc[6] = fmaf(w[k], hb[k].z - bf2f((unsigned short)rv[k][6]), acc[6]);
                acc[7] = fmaf(w[k], hb[k].w - bf2f((unsigned short)rv[k][7]), acc[7]);
            }
        }
    }

    // mean + bf16 pack; lane c writes its own 16 B of row (wav*4 + q)
    {
        float inv = 1.f / (float)cnt;  // cnt >= 1 (cover edges)
        int row = wav * 4 + q;
        uint4 pk;
        pk.x = (unsigned)f2bf(acc[0] * inv) | ((unsigned)f2bf(acc[1] * inv) << 16);
        pk.y = (unsigned)f2bf(acc[2] * inv) | ((unsigned)f2bf(acc[3] * inv) << 16);
        pk.z = (unsigned)f2bf(acc[4] * inv) | ((unsigned)f2bf(acc[5] * inv) << 16);
        pk.w = (unsigned)f2bf(acc[6] * inv) | ((unsigned)f2bf(acc[7] * inv) << 16);
        int off = (row * 256 + c * 16) ^ ((row & 7) << 4);
        *reinterpret_cast<uint4*>((char*)Xl + off) = pk;
    }

    __syncthreads();  // x-tile staged

    // A-frags: lane row = c, k = ks*32 + q*8 + j
    bf16x8 afr[4];
    #pragma unroll
    for (int ks = 0; ks < 4; ++ks) {
        int off = (c * 256 + ks * 64 + q * 16) ^ ((c & 7) << 4);
        afr[ks] = *reinterpret_cast<const bf16x8*>((const char*)Xl + off);
    }

    // wave computes cols wav*32 .. wav*32+31 (n = wav*2, wav*2+1)
    size_t rowbase = (size_t)blockIdx.x * 16;
    #pragma unroll
    for (int n2 = 0; n2 < 2; ++n2) {
        int n = wav * 2 + n2;
        f32x4 accv = (f32x4){0.f, 0.f, 0.f, 0.f};
        #pragma unroll
        for (int ks = 0; ks < 4; ++ks) {
            bf16x8 bfr = reinterpret_cast<const bf16x8*>(Wbf)[(n * 4 + ks) * 64 + l];
            accv = __builtin_amdgcn_mfma_f32_16x16x32_bf16(afr[ks], bfr, accv, 0, 0, 0);
        }
        #pragma unroll
        for (int j = 0; j < 4; ++j)
            out[(rowbase + q * 4 + j) * CDIM + n * 16 + c] = accv[j];
    }
}

extern "C" void kernel_launch(void* const* d_in, const int* in_sizes, int n_in,
                              void* d_out, int out_size, void* d_ws, size_t ws_size,
                              hipStream_t stream) {
    const float* node = (const float*)d_in[0];
    const int*   eidx = (const int*)d_in[1];
    const float* rel  = (const float*)d_in[2];
    const float* W    = (const float*)d_in[3];
    float* out = (float*)d_out;

    // ws: count u32[SEGS] @0 (400000); payload u32[SEGS*CAP] @400000
    //     (ends 13200000); Wbf 32 KB @13200000; relb 16 KB @13232768;
    //     nodeb bf16[SEGS*CDIM] @13249152 (ends 38849152)
    unsigned* count   = (unsigned*)d_ws;
    unsigned* payload = (unsigned*)((char*)d_ws + 400000);
    unsigned* Wbf     = (unsigned*)((char*)d_ws + 13200000);
    unsigned* relb    = (unsigned*)((char*)d_ws + 13232768);
    unsigned short* nodeb = (unsigned short*)((char*)d_ws + 13249152);
    const size_t NEED = 13249152ull + (size_t)SEGS * CDIM * 2;
    const bool use_bf = (ws_size >= NEED);

    hipMemsetAsync(count, 0, (size_t)SEGS * sizeof(unsigned), stream);

    binscatter_k<<<2 * (EB4 + 1), 256, 0, stream>>>(eidx, count, payload, W, Wbf,
                                                    rel, relb, node, nodeb,
                                                    use_bf ? 1 : 0);

    if (use_bf)
        fused_k<true><<<SEGS / 16, 256, 0, stream>>>(nodeb, relb, count, payload, Wbf, out);
    else
        fused_k<false><<<SEGS / 16, 256, 0, stream>>>(node, relb, count, payload, Wbf, out);
}